// Round 10
// baseline (157.345 us; speedup 1.0000x reference)
//
#include <hip/hip_runtime.h>
#include <cfloat>

// Problem constants (fixed by setup_inputs)
#define C_DIM   256
#define HW      1024
#define N_ROWS  32768
#define K_CODES 1024
#define ROWS    32            // rows per workgroup
#define NCHUNK  16            // 1024 codes / 64 per chunk; wave slice = 16 codes
#define WCHUNK_BYTES 8192     // 16 codes * 256 * 2B fp16
#define LISTCAP 128           // per-wave candidate list
#define DELTA   0.008f

#define OUT_ELEMS 8388608
#define LOSS_OFF  8388608
#define IDX_OFF   8388611

typedef _Float16 half8 __attribute__((ext_vector_type(8)));
typedef _Float16 f16x4 __attribute__((ext_vector_type(4)));
typedef float    f32x4 __attribute__((ext_vector_type(4)));

#define AS1 __attribute__((address_space(1)))
#define AS3 __attribute__((address_space(3)))

// dynamic LDS layout (bytes); ebuf+en region reused as qt[32][258] f32 (33024B) in the tail
#define OFF_EBUF  0                    // 4 waves * 1 buf * 8192 = 32768
#define OFF_EN    32768                // 1024*4 = 4096 -> 36864
#define OFF_S32   36864                // 32*4 -> 36992
#define OFF_M1W   36992                // 4*32*4 -> 37504
#define OFF_THR   37504                // 32*4 -> 37632
#define OFF_RES   37632                // 32*8 -> 37888
#define OFF_FIDX  37888                // 32*4 -> 38016
#define OFF_LCNT  38016                // pad -> 38144
#define OFF_LMETA 38144                // 4*128*4 -> 40192
#define SMEM_BYTES 40448               // 4 blocks/CU (4x40448 = 161792 <= 163840)

#define QT_STRIDE 258

// min across the 16-lane row group (lanes sharing lane>>4)
#define DPP_MIN(x, ctrl) fminf((x), __int_as_float(__builtin_amdgcn_update_dpp(0, __float_as_int(x), (ctrl), 0xf, 0xf, true)))

// Kernel 1: codebook prep — fp32 norms (fp64-accurate) + fp16 copy, pre-swizzled.
// ws fp16 layout: byte = (k/32)*16384 + (k%32)*512 + ((c*2) ^ ((k&15)<<4) ^ ((k&1)<<8))
__global__ void prep_kernel(const float* __restrict__ cb, float* __restrict__ enorm,
                            char* __restrict__ cb16) {
    int k = blockIdx.x * 4 + (threadIdx.x >> 6);
    int lane = threadIdx.x & 63;
    float4 v = *(const float4*)(cb + k * C_DIM + lane * 4);
    double s = (double)v.x * v.x + (double)v.y * v.y + (double)v.z * v.z + (double)v.w * v.w;
    #pragma unroll
    for (int m = 1; m < 64; m <<= 1) s += __shfl_xor(s, m, 64);
    if (lane == 0) enorm[k] = (float)s;
    f16x4 h;
    h[0] = (_Float16)v.x; h[1] = (_Float16)v.y; h[2] = (_Float16)v.z; h[3] = (_Float16)v.w;
    int dst = ((k >> 5) << 14) + ((k & 31) << 9)
            + ((lane * 8) ^ ((k & 15) << 4) ^ ((k & 1) << 8));
    *(f16x4*)(cb16 + dst) = h;
}

// Kernel 2: single-sweep fp16-MFMA prune, in-register top-2 per lane-slot,
// wave-private single-buffer staging (1-ahead prefetch), 4 blocks/CU.
__global__ __launch_bounds__(256, 4) void vq_main(
    const float* __restrict__ x, const float* __restrict__ cb,
    const float* __restrict__ enorm_g, const char* __restrict__ cb16,
    float* __restrict__ out, float* __restrict__ idx_out, float* __restrict__ t2_out)
{
    extern __shared__ char smem[];
    float* qt      = (float*)(smem + OFF_EBUF);   // tail-phase alias (ebuf+en dead)
    float* en_lds  = (float*)(smem + OFF_EN);
    float* S32     = (float*)(smem + OFF_S32);
    float* m1w     = (float*)(smem + OFF_M1W);
    float* thr     = (float*)(smem + OFF_THR);
    unsigned long long* res = (unsigned long long*)(smem + OFF_RES);
    int*   fidx    = (int*)(smem + OFF_FIDX);
    int*   lcnt    = (int*)(smem + OFF_LCNT);
    unsigned int* lmeta = (unsigned int*)(smem + OFF_LMETA);

    const int t    = threadIdx.x;
    const int lane = t & 63;
    const int wq   = t >> 6;           // wave's code-quarter within each 64-code chunk
    const int l15  = lane & 15;
    const int l4   = lane >> 4;
    const int row0 = blockIdx.x * ROWS;
    const int b    = row0 >> 10;
    const int hw0  = row0 & 1023;
    const float* xb = x + b * (C_DIM * HW) + hw0;

    char* ebw = smem + OFF_EBUF + wq * WCHUNK_BYTES;   // wave-private 8KB single buffer

    // ---- issue wave-private staging for chunk 0 (lands under the A-build) ----
    {
        const char* src = cb16 + wq * WCHUNK_BYTES;    // ch=0: base + wq*8192
        #pragma unroll
        for (int i = 0; i < 8; i++) {
            __builtin_amdgcn_global_load_lds((const AS1 unsigned int*)(src + i * 1024 + lane * 16),
                                             (AS3 unsigned int*)(ebw + i * 1024), 16, 0, 0);
        }
    }

    // ---- stage enorm + reset counters ----
    *(float4*)&en_lds[t * 4] = *(const float4*)(enorm_g + t * 4);
    if (t < 4) lcnt[t] = 0;

    // ---- A fragments direct from global x (fp16, scaled by -2) + fp64 S32 ----
    // rows rt*16 + l15 (all 32 rows of this block; every wave builds the same A)
    half8 af[2][8];
    double s64[2] = {0.0, 0.0};
    #pragma unroll
    for (int rt = 0; rt < 2; rt++) {
        const float* xr = xb + rt * 16 + l15;
        #pragma unroll
        for (int kk = 0; kk < 8; kk++) {
            float v[8];
            #pragma unroll
            for (int j = 0; j < 8; j++) v[j] = xr[(kk * 32 + l4 * 8 + j) * HW];
            #pragma unroll
            for (int j = 0; j < 8; j++) s64[rt] = fma((double)v[j], (double)v[j], s64[rt]);
            half8 h;
            #pragma unroll
            for (int j = 0; j < 8; j++) h[j] = (_Float16)(-2.0f * v[j]);
            af[rt][kk] = h;
        }
    }
    #pragma unroll
    for (int rt = 0; rt < 2; rt++) {
        s64[rt] += __shfl_xor(s64[rt], 16, 64);
        s64[rt] += __shfl_xor(s64[rt], 32, 64);
    }
    if (wq == 0 && l4 == 0) {
        S32[l15]      = (float)s64[0];
        S32[16 + l15] = (float)s64[1];
    }
    __syncthreads();   // S32/en visible; chunk 0 landed (full drain, once)

    const int swzB = (l15 << 4) ^ ((l15 & 1) << 8);
    const int bofs = (l15 << 9);

    // ====== SINGLE SWEEP: MFMA + lane-local top-2 per slot (no barriers) ======
    float s1v[2][4], s2v[2][4];
    int   c1v[2][4], c2v[2][4];
    #pragma unroll
    for (int rt = 0; rt < 2; rt++)
        #pragma unroll
        for (int r2 = 0; r2 < 4; r2++) {
            s1v[rt][r2] = FLT_MAX; s2v[rt][r2] = FLT_MAX;
            c1v[rt][r2] = 0;       c2v[rt][r2] = 0;
        }

    for (int ch = 0; ch < NCHUNK; ch++) {
        if (ch) { asm volatile("s_waitcnt vmcnt(0)" ::: "memory"); }   // chunk ch landed
        __builtin_amdgcn_sched_barrier(0);

        half8 bf[8];
        #pragma unroll
        for (int kk = 0; kk < 8; kk++)
            bf[kk] = *(const half8*)(ebw + bofs + (((kk << 6) | (l4 << 4)) ^ swzB));
        asm volatile("s_waitcnt lgkmcnt(0)" ::: "memory");   // bf in regs; buffer dead
        __builtin_amdgcn_sched_barrier(0);

        if (ch + 1 < NCHUNK) {       // refill same buffer for ch+1
            const char* src = cb16 + (ch + 1) * 32768 + wq * WCHUNK_BYTES;
            #pragma unroll
            for (int i = 0; i < 8; i++) {
                __builtin_amdgcn_global_load_lds((const AS1 unsigned int*)(src + i * 1024 + lane * 16),
                                                 (AS3 unsigned int*)(ebw + i * 1024), 16, 0, 0);
            }
        }

        const float en = en_lds[ch * 64 + wq * 16 + l15];
        f32x4 acc0 = {en, en, en, en};
        f32x4 acc1 = {en, en, en, en};
        #pragma unroll
        for (int kk = 0; kk < 8; kk++) {
            acc0 = __builtin_amdgcn_mfma_f32_16x16x32_f16(af[0][kk], bf[kk], acc0, 0, 0, 0);
            acc1 = __builtin_amdgcn_mfma_f32_16x16x32_f16(af[1][kk], bf[kk], acc1, 0, 0, 0);
        }
        // lane-local top-2 update per slot (no cross-lane ops)
        #pragma unroll
        for (int r2 = 0; r2 < 4; r2++) {
            float s0 = acc0[r2];
            if (s0 < s1v[0][r2]) {
                s2v[0][r2] = s1v[0][r2]; c2v[0][r2] = c1v[0][r2];
                s1v[0][r2] = s0;         c1v[0][r2] = ch;
            } else if (s0 < s2v[0][r2]) {
                s2v[0][r2] = s0;         c2v[0][r2] = ch;
            }
            float s1 = acc1[r2];
            if (s1 < s1v[1][r2]) {
                s2v[1][r2] = s1v[1][r2]; c2v[1][r2] = c1v[1][r2];
                s1v[1][r2] = s1;         c1v[1][r2] = ch;
            } else if (s1 < s2v[1][r2]) {
                s2v[1][r2] = s1;         c2v[1][r2] = ch;
            }
        }
    }

    // ---- one-time reduce: DPP over 16 lanes -> per-row wave min; cross-wave merge ----
    #pragma unroll
    for (int rt = 0; rt < 2; rt++) {
        #pragma unroll
        for (int r2 = 0; r2 < 4; r2++) {
            float m = s1v[rt][r2];
            m = DPP_MIN(m, 0xB1);
            m = DPP_MIN(m, 0x4E);
            m = DPP_MIN(m, 0x141);
            m = DPP_MIN(m, 0x140);   // min over this wave's 16 code-columns
            if (l15 == 0) m1w[wq * 32 + rt * 16 + l4 * 4 + r2] = m;
        }
    }
    __syncthreads();
    if (t < 32) {
        thr[t] = fminf(fminf(m1w[t], m1w[32 + t]), fminf(m1w[64 + t], m1w[96 + t])) + DELTA;
        res[t] = ~0ull;
    }
    __syncthreads();

    // ---- push candidates from register top-2 (once, tiny) ----
    #pragma unroll
    for (int rt = 0; rt < 2; rt++) {
        #pragma unroll
        for (int r2 = 0; r2 < 4; r2++) {
            int row_l = rt * 16 + l4 * 4 + r2;
            float tr = thr[row_l];
            if (s1v[rt][r2] < tr) {
                int code = c1v[rt][r2] * 64 + wq * 16 + l15;
                int slot = atomicAdd(&lcnt[wq], 1);
                if (slot < LISTCAP)
                    lmeta[wq * LISTCAP + slot] = ((unsigned)row_l << 16) | (unsigned)code;
            }
            if (s2v[rt][r2] < tr) {
                int code = c2v[rt][r2] * 64 + wq * 16 + l15;
                int slot = atomicAdd(&lcnt[wq], 1);
                if (slot < LISTCAP)
                    lmeta[wq * LISTCAP + slot] = ((unsigned)row_l << 16) | (unsigned)code;
            }
        }
    }
    __syncthreads();

    // ---- rescore survivors: fp64 dot (z re-read from global) -> fp32 ref sim ----
    {
        int n = lcnt[wq]; if (n > LISTCAP) n = LISTCAP;
        for (int base = 0; base < n; base += 4) {
            int it = base + l4;
            if (it < n) {
                unsigned meta = lmeta[wq * LISTCAP + it];
                int row  = (int)(meta >> 16);
                int code = (int)(meta & 1023u);
                const float* xr = xb + row;            // element c at xr[c*HW]
                const float* er = cb + code * C_DIM;
                double acc = 0.0;
                #pragma unroll
                for (int s2 = 0; s2 < 16; s2++) {
                    int c = l15 + 16 * s2;
                    acc = fma((double)xr[(size_t)c * HW], (double)er[c], acc);
                }
                acc += __shfl_xor(acc, 1, 64);
                acc += __shfl_xor(acc, 2, 64);
                acc += __shfl_xor(acc, 4, 64);
                acc += __shfl_xor(acc, 8, 64);
                if (l15 == 0) {
                    float Mf = (float)acc;
                    float t2 = __fadd_rn(__fsub_rn(S32[row], __fmul_rn(2.0f, Mf)), en_lds[code]);
                    unsigned long long pk =
                        ((unsigned long long)__float_as_uint(t2) << 32) | (unsigned long long)(unsigned)code;
                    atomicMin(&res[row], pk);
                }
            }
        }
    }
    __syncthreads();

    if (t < 32) {
        unsigned long long v = res[t];
        int code = (int)(v & 1023u);
        fidx[t] = code;
        idx_out[row0 + t] = (float)code;
        t2_out[row0 + t] = __uint_as_float((unsigned)(v >> 32));
    }
    __syncthreads();

    // ---- quantized output (NCHW) via LDS bounce: coalesced reads AND stores ----
    {
        for (int idx = t; idx < 32 * 64; idx += 256) {
            int r  = idx >> 6;         // 0..31
            int c4 = idx & 63;
            const float* er = cb + fidx[r] * C_DIM;
            *(float4*)&qt[r * QT_STRIDE + c4 * 4] = *(const float4*)(er + c4 * 4);
        }
        __syncthreads();
        float* ob = out + b * (C_DIM * HW) + hw0;
        int rr = t & 31;
        int cg = t >> 5;               // 0..7
        for (int cc = cg; cc < C_DIM; cc += 8) {
            ob[cc * HW + rr] = qt[rr * QT_STRIDE + cc];
        }
    }
}

// Kernel 3: deterministic loss reduction over per-row t2
__global__ void loss_kernel(const float* __restrict__ t2min, float* __restrict__ losses) {
    __shared__ double sh[256];
    int t = threadIdx.x;
    double a = 0.0;
    const int per = N_ROWS / 256;
    for (int i = t * per; i < t * per + per; i++) a += (double)t2min[i];
    sh[t] = a;
    __syncthreads();
    for (int s = 128; s > 0; s >>= 1) {
        if (t < s) sh[t] += sh[t + s];
        __syncthreads();
    }
    if (t == 0) {
        double M = sh[0] / (double)OUT_ELEMS;
        losses[0] = (float)(1.25 * M);   // quantizer_loss
        losses[1] = (float)(0.25 * M);   // e_latent_loss
        losses[2] = (float)(M);          // q_latent_loss
    }
}

extern "C" void kernel_launch(void* const* d_in, const int* in_sizes, int n_in,
                              void* d_out, int out_size, void* d_ws, size_t ws_size,
                              hipStream_t stream) {
    const float* x  = (const float*)d_in[0];
    const float* cb = (const float*)d_in[1];
    float* out     = (float*)d_out;
    float* losses  = out + LOSS_OFF;
    float* idx_out = out + IDX_OFF;

    char*  cb16     = (char*)d_ws;                               // 524288 B
    float* t2ws     = (float*)((char*)d_ws + 524288);            // 131072 B
    float* enorm_ws = (float*)((char*)d_ws + 524288 + 131072);   // 4096 B

    hipFuncSetAttribute(reinterpret_cast<const void*>(vq_main),
                        hipFuncAttributeMaxDynamicSharedMemorySize, SMEM_BYTES);

    prep_kernel<<<K_CODES / 4, 256, 0, stream>>>(cb, enorm_ws, cb16);
    vq_main<<<N_ROWS / ROWS, 256, SMEM_BYTES, stream>>>(x, cb, enorm_ws, cb16, out, idx_out, t2ws);
    loss_kernel<<<1, 256, 0, stream>>>(t2ws, losses);
}

// Round 11
// 105.799 us; speedup vs baseline: 1.4872x; 1.4872x over previous
//
#include <hip/hip_runtime.h>
#include <cfloat>

// Problem constants (fixed by setup_inputs)
#define C_DIM   256
#define HW      1024
#define N_ROWS  32768
#define K_CODES 1024
#define ROWS    32            // rows per workgroup
#define NCHUNK  16            // 1024 codes / 64 per chunk; wave slice = 16 codes
#define WCHUNK_BYTES 8192     // 16 codes * 256 * 2B fp16
#define LISTCAP 128           // per-wave candidate list
#define DELTA   0.008f

#define OUT_ELEMS 8388608
#define LOSS_OFF  8388608
#define IDX_OFF   8388611

typedef _Float16 half8 __attribute__((ext_vector_type(8)));
typedef _Float16 f16x4 __attribute__((ext_vector_type(4)));
typedef float    f32x4 __attribute__((ext_vector_type(4)));

#define AS1 __attribute__((address_space(1)))
#define AS3 __attribute__((address_space(3)))

// dynamic LDS layout (bytes); ebuf+en region reused as qt[32][258] f32 (33024B) in the tail
#define OFF_EBUF  0                    // 4 waves * 1 buf * 8192 = 32768
#define OFF_EN    32768                // 1024*4 = 4096 -> 36864
#define OFF_S32   36864                // 32*4 -> 36992
#define OFF_M1W   36992                // 4*32*4 -> 37504
#define OFF_THR   37504                // 32*4 -> 37632
#define OFF_RES   37632                // 32*8 -> 37888
#define OFF_FIDX  37888                // 32*4 -> 38016
#define OFF_LCNT  38016                // pad -> 38144
#define OFF_LMETA 38144                // 4*128*4 -> 40192
#define SMEM_BYTES 40448               // LDS allows 4/CU; VGPR (170 @ 3 w/SIMD) binds at 3

#define QT_STRIDE 258

// min across the 16-lane row group (lanes sharing lane>>4)
#define DPP_MIN(x, ctrl) fminf((x), __int_as_float(__builtin_amdgcn_update_dpp(0, __float_as_int(x), (ctrl), 0xf, 0xf, true)))

// Kernel 1: codebook prep — fp32 norms (fp64-accurate) + fp16 copy, pre-swizzled.
// ws fp16 layout: byte = (k/32)*16384 + (k%32)*512 + ((c*2) ^ ((k&15)<<4) ^ ((k&1)<<8))
__global__ void prep_kernel(const float* __restrict__ cb, float* __restrict__ enorm,
                            char* __restrict__ cb16) {
    int k = blockIdx.x * 4 + (threadIdx.x >> 6);
    int lane = threadIdx.x & 63;
    float4 v = *(const float4*)(cb + k * C_DIM + lane * 4);
    double s = (double)v.x * v.x + (double)v.y * v.y + (double)v.z * v.z + (double)v.w * v.w;
    #pragma unroll
    for (int m = 1; m < 64; m <<= 1) s += __shfl_xor(s, m, 64);
    if (lane == 0) enorm[k] = (float)s;
    f16x4 h;
    h[0] = (_Float16)v.x; h[1] = (_Float16)v.y; h[2] = (_Float16)v.z; h[3] = (_Float16)v.w;
    int dst = ((k >> 5) << 14) + ((k & 31) << 9)
            + ((lane * 8) ^ ((k & 15) << 4) ^ ((k & 1) << 8));
    *(f16x4*)(cb16 + dst) = h;
}

// Kernel 2: single-sweep fp16-MFMA prune, in-register top-2 per lane-slot,
// wave-private single-buffer staging (1-ahead prefetch), 3 waves/SIMD (no spill).
__global__ __launch_bounds__(256, 3) void vq_main(
    const float* __restrict__ x, const float* __restrict__ cb,
    const float* __restrict__ enorm_g, const char* __restrict__ cb16,
    float* __restrict__ out, float* __restrict__ idx_out, float* __restrict__ t2_out)
{
    extern __shared__ char smem[];
    float* qt      = (float*)(smem + OFF_EBUF);   // tail-phase alias (ebuf+en dead)
    float* en_lds  = (float*)(smem + OFF_EN);
    float* S32     = (float*)(smem + OFF_S32);
    float* m1w     = (float*)(smem + OFF_M1W);
    float* thr     = (float*)(smem + OFF_THR);
    unsigned long long* res = (unsigned long long*)(smem + OFF_RES);
    int*   fidx    = (int*)(smem + OFF_FIDX);
    int*   lcnt    = (int*)(smem + OFF_LCNT);
    unsigned int* lmeta = (unsigned int*)(smem + OFF_LMETA);

    const int t    = threadIdx.x;
    const int lane = t & 63;
    const int wq   = t >> 6;           // wave's code-quarter within each 64-code chunk
    const int l15  = lane & 15;
    const int l4   = lane >> 4;
    const int row0 = blockIdx.x * ROWS;
    const int b    = row0 >> 10;
    const int hw0  = row0 & 1023;
    const float* xb = x + b * (C_DIM * HW) + hw0;

    char* ebw = smem + OFF_EBUF + wq * WCHUNK_BYTES;   // wave-private 8KB single buffer

    // ---- issue wave-private staging for chunk 0 (lands under the A-build) ----
    {
        const char* src = cb16 + wq * WCHUNK_BYTES;    // ch=0: base + wq*8192
        #pragma unroll
        for (int i = 0; i < 8; i++) {
            __builtin_amdgcn_global_load_lds((const AS1 unsigned int*)(src + i * 1024 + lane * 16),
                                             (AS3 unsigned int*)(ebw + i * 1024), 16, 0, 0);
        }
    }

    // ---- stage enorm + reset counters ----
    *(float4*)&en_lds[t * 4] = *(const float4*)(enorm_g + t * 4);
    if (t < 4) lcnt[t] = 0;

    // ---- A fragments direct from global x (fp16, scaled by -2) + fp64 S32 ----
    // rows rt*16 + l15 (all 32 rows of this block; every wave builds the same A)
    half8 af[2][8];
    double s64[2] = {0.0, 0.0};
    #pragma unroll
    for (int rt = 0; rt < 2; rt++) {
        const float* xr = xb + rt * 16 + l15;
        #pragma unroll
        for (int kk = 0; kk < 8; kk++) {
            float v[8];
            #pragma unroll
            for (int j = 0; j < 8; j++) v[j] = xr[(kk * 32 + l4 * 8 + j) * HW];
            #pragma unroll
            for (int j = 0; j < 8; j++) s64[rt] = fma((double)v[j], (double)v[j], s64[rt]);
            half8 h;
            #pragma unroll
            for (int j = 0; j < 8; j++) h[j] = (_Float16)(-2.0f * v[j]);
            af[rt][kk] = h;
        }
    }
    #pragma unroll
    for (int rt = 0; rt < 2; rt++) {
        s64[rt] += __shfl_xor(s64[rt], 16, 64);
        s64[rt] += __shfl_xor(s64[rt], 32, 64);
    }
    if (wq == 0 && l4 == 0) {
        S32[l15]      = (float)s64[0];
        S32[16 + l15] = (float)s64[1];
    }
    __syncthreads();   // S32/en visible; chunk 0 landed (full drain, once)

    const int swzB = (l15 << 4) ^ ((l15 & 1) << 8);
    const int bofs = (l15 << 9);

    // ====== SINGLE SWEEP: MFMA + lane-local top-2 per slot (no barriers) ======
    float s1v[2][4], s2v[2][4];
    int   c1v[2][4], c2v[2][4];
    #pragma unroll
    for (int rt = 0; rt < 2; rt++)
        #pragma unroll
        for (int r2 = 0; r2 < 4; r2++) {
            s1v[rt][r2] = FLT_MAX; s2v[rt][r2] = FLT_MAX;
            c1v[rt][r2] = 0;       c2v[rt][r2] = 0;
        }

    for (int ch = 0; ch < NCHUNK; ch++) {
        if (ch) { asm volatile("s_waitcnt vmcnt(0)" ::: "memory"); }   // chunk ch landed
        __builtin_amdgcn_sched_barrier(0);

        half8 bf[8];
        #pragma unroll
        for (int kk = 0; kk < 8; kk++)
            bf[kk] = *(const half8*)(ebw + bofs + (((kk << 6) | (l4 << 4)) ^ swzB));
        asm volatile("s_waitcnt lgkmcnt(0)" ::: "memory");   // bf in regs; buffer dead
        __builtin_amdgcn_sched_barrier(0);

        if (ch + 1 < NCHUNK) {       // refill same buffer for ch+1
            const char* src = cb16 + (ch + 1) * 32768 + wq * WCHUNK_BYTES;
            #pragma unroll
            for (int i = 0; i < 8; i++) {
                __builtin_amdgcn_global_load_lds((const AS1 unsigned int*)(src + i * 1024 + lane * 16),
                                                 (AS3 unsigned int*)(ebw + i * 1024), 16, 0, 0);
            }
        }

        const float en = en_lds[ch * 64 + wq * 16 + l15];
        f32x4 acc0 = {en, en, en, en};
        f32x4 acc1 = {en, en, en, en};
        #pragma unroll
        for (int kk = 0; kk < 8; kk++) {
            acc0 = __builtin_amdgcn_mfma_f32_16x16x32_f16(af[0][kk], bf[kk], acc0, 0, 0, 0);
            acc1 = __builtin_amdgcn_mfma_f32_16x16x32_f16(af[1][kk], bf[kk], acc1, 0, 0, 0);
        }
        // lane-local top-2 update per slot (no cross-lane ops)
        #pragma unroll
        for (int r2 = 0; r2 < 4; r2++) {
            float s0 = acc0[r2];
            if (s0 < s1v[0][r2]) {
                s2v[0][r2] = s1v[0][r2]; c2v[0][r2] = c1v[0][r2];
                s1v[0][r2] = s0;         c1v[0][r2] = ch;
            } else if (s0 < s2v[0][r2]) {
                s2v[0][r2] = s0;         c2v[0][r2] = ch;
            }
            float s1 = acc1[r2];
            if (s1 < s1v[1][r2]) {
                s2v[1][r2] = s1v[1][r2]; c2v[1][r2] = c1v[1][r2];
                s1v[1][r2] = s1;         c1v[1][r2] = ch;
            } else if (s1 < s2v[1][r2]) {
                s2v[1][r2] = s1;         c2v[1][r2] = ch;
            }
        }
    }

    // ---- one-time reduce: DPP over 16 lanes -> per-row wave min; cross-wave merge ----
    #pragma unroll
    for (int rt = 0; rt < 2; rt++) {
        #pragma unroll
        for (int r2 = 0; r2 < 4; r2++) {
            float m = s1v[rt][r2];
            m = DPP_MIN(m, 0xB1);
            m = DPP_MIN(m, 0x4E);
            m = DPP_MIN(m, 0x141);
            m = DPP_MIN(m, 0x140);   // min over this wave's 16 code-columns
            if (l15 == 0) m1w[wq * 32 + rt * 16 + l4 * 4 + r2] = m;
        }
    }
    __syncthreads();
    if (t < 32) {
        thr[t] = fminf(fminf(m1w[t], m1w[32 + t]), fminf(m1w[64 + t], m1w[96 + t])) + DELTA;
        res[t] = ~0ull;
    }
    __syncthreads();

    // ---- push candidates from register top-2 (once, tiny) ----
    #pragma unroll
    for (int rt = 0; rt < 2; rt++) {
        #pragma unroll
        for (int r2 = 0; r2 < 4; r2++) {
            int row_l = rt * 16 + l4 * 4 + r2;
            float tr = thr[row_l];
            if (s1v[rt][r2] < tr) {
                int code = c1v[rt][r2] * 64 + wq * 16 + l15;
                int slot = atomicAdd(&lcnt[wq], 1);
                if (slot < LISTCAP)
                    lmeta[wq * LISTCAP + slot] = ((unsigned)row_l << 16) | (unsigned)code;
            }
            if (s2v[rt][r2] < tr) {
                int code = c2v[rt][r2] * 64 + wq * 16 + l15;
                int slot = atomicAdd(&lcnt[wq], 1);
                if (slot < LISTCAP)
                    lmeta[wq * LISTCAP + slot] = ((unsigned)row_l << 16) | (unsigned)code;
            }
        }
    }
    __syncthreads();

    // ---- rescore survivors: fp64 dot (z re-read from global) -> fp32 ref sim ----
    {
        int n = lcnt[wq]; if (n > LISTCAP) n = LISTCAP;
        for (int base = 0; base < n; base += 4) {
            int it = base + l4;
            if (it < n) {
                unsigned meta = lmeta[wq * LISTCAP + it];
                int row  = (int)(meta >> 16);
                int code = (int)(meta & 1023u);
                const float* xr = xb + row;            // element c at xr[c*HW]
                const float* er = cb + code * C_DIM;
                double acc = 0.0;
                #pragma unroll
                for (int s2 = 0; s2 < 16; s2++) {
                    int c = l15 + 16 * s2;
                    acc = fma((double)xr[(size_t)c * HW], (double)er[c], acc);
                }
                acc += __shfl_xor(acc, 1, 64);
                acc += __shfl_xor(acc, 2, 64);
                acc += __shfl_xor(acc, 4, 64);
                acc += __shfl_xor(acc, 8, 64);
                if (l15 == 0) {
                    float Mf = (float)acc;
                    float t2 = __fadd_rn(__fsub_rn(S32[row], __fmul_rn(2.0f, Mf)), en_lds[code]);
                    unsigned long long pk =
                        ((unsigned long long)__float_as_uint(t2) << 32) | (unsigned long long)(unsigned)code;
                    atomicMin(&res[row], pk);
                }
            }
        }
    }
    __syncthreads();

    if (t < 32) {
        unsigned long long v = res[t];
        int code = (int)(v & 1023u);
        fidx[t] = code;
        idx_out[row0 + t] = (float)code;
        t2_out[row0 + t] = __uint_as_float((unsigned)(v >> 32));
    }
    __syncthreads();

    // ---- quantized output (NCHW) via LDS bounce: coalesced reads AND stores ----
    {
        for (int idx = t; idx < 32 * 64; idx += 256) {
            int r  = idx >> 6;         // 0..31
            int c4 = idx & 63;
            const float* er = cb + fidx[r] * C_DIM;
            *(float4*)&qt[r * QT_STRIDE + c4 * 4] = *(const float4*)(er + c4 * 4);
        }
        __syncthreads();
        float* ob = out + b * (C_DIM * HW) + hw0;
        int rr = t & 31;
        int cg = t >> 5;               // 0..7
        for (int cc = cg; cc < C_DIM; cc += 8) {
            ob[cc * HW + rr] = qt[rr * QT_STRIDE + cc];
        }
    }
}

// Kernel 3: deterministic loss reduction over per-row t2
__global__ void loss_kernel(const float* __restrict__ t2min, float* __restrict__ losses) {
    __shared__ double sh[256];
    int t = threadIdx.x;
    double a = 0.0;
    const int per = N_ROWS / 256;
    for (int i = t * per; i < t * per + per; i++) a += (double)t2min[i];
    sh[t] = a;
    __syncthreads();
    for (int s = 128; s > 0; s >>= 1) {
        if (t < s) sh[t] += sh[t + s];
        __syncthreads();
    }
    if (t == 0) {
        double M = sh[0] / (double)OUT_ELEMS;
        losses[0] = (float)(1.25 * M);   // quantizer_loss
        losses[1] = (float)(0.25 * M);   // e_latent_loss
        losses[2] = (float)(M);          // q_latent_loss
    }
}

extern "C" void kernel_launch(void* const* d_in, const int* in_sizes, int n_in,
                              void* d_out, int out_size, void* d_ws, size_t ws_size,
                              hipStream_t stream) {
    const float* x  = (const float*)d_in[0];
    const float* cb = (const float*)d_in[1];
    float* out     = (float*)d_out;
    float* losses  = out + LOSS_OFF;
    float* idx_out = out + IDX_OFF;

    char*  cb16     = (char*)d_ws;                               // 524288 B
    float* t2ws     = (float*)((char*)d_ws + 524288);            // 131072 B
    float* enorm_ws = (float*)((char*)d_ws + 524288 + 131072);   // 4096 B

    hipFuncSetAttribute(reinterpret_cast<const void*>(vq_main),
                        hipFuncAttributeMaxDynamicSharedMemorySize, SMEM_BYTES);

    prep_kernel<<<K_CODES / 4, 256, 0, stream>>>(cb, enorm_ws, cb16);
    vq_main<<<N_ROWS / ROWS, 256, SMEM_BYTES, stream>>>(x, cb, enorm_ws, cb16, out, idx_out, t2ws);
    loss_kernel<<<1, 256, 0, stream>>>(t2ws, losses);
}

// Round 13
// 86.229 us; speedup vs baseline: 1.8247x; 1.2270x over previous
//
#include <hip/hip_runtime.h>
#include <cfloat>

// Problem constants (fixed by setup_inputs)
#define C_DIM   256
#define HW      1024
#define N_ROWS  32768
#define K_CODES 1024
#define ROWS    32            // rows per workgroup (2 row-groups x 16)
#define NCHUNK  32            // per-wave: 32 chunks x 16 codes = 512 codes (chalf)
#define WCHUNK_BYTES 8192     // 16 codes * 256 * 2B fp16
#define LISTCAP 128           // per-wave candidate list
#define DELTA   0.008f

#define OUT_ELEMS 8388608
#define LOSS_OFF  8388608
#define IDX_OFF   8388611

typedef _Float16 half8 __attribute__((ext_vector_type(8)));
typedef _Float16 f16x4 __attribute__((ext_vector_type(4)));
typedef float    f32x4 __attribute__((ext_vector_type(4)));

#define AS1 __attribute__((address_space(1)))
#define AS3 __attribute__((address_space(3)))

// dynamic LDS layout (bytes); qt[32][258] f32 (33024B) tail-aliases ebuf+en (both dead)
#define OFF_EBUF  0                    // 4 waves * 1 buf * 8192 = 32768
#define OFF_EN    32768                // 1024*4 -> 36864
#define OFF_S32   36864                // 32*4 -> 36992
#define OFF_M1W   36992                // 4*16*4 -> 37248
#define OFF_THR   37248                // 32*4 -> 37376
#define OFF_RES   37376                // 32*8 -> 37632
#define OFF_FIDX  37632                // 32*4 -> 37760
#define OFF_LCNT  37760                // pad -> 37888
#define OFF_LMETA 37888                // 4*128*4 -> 39936
#define SMEM_BYTES 39936               // 4 blocks/CU by LDS (4x39936 <= 163840)

#define QT_STRIDE 258

// min across the 16-lane row group (lanes sharing lane>>4)
#define DPP_MIN(x, ctrl) fminf((x), __int_as_float(__builtin_amdgcn_update_dpp(0, __float_as_int(x), (ctrl), 0xf, 0xf, true)))

// Kernel 1: codebook prep — fp32 norms (fp64-accurate) + fp16 copy, pre-swizzled.
// 16-code groups: byte = (k/16)*8192 + (k%16)*512 + ((c*2) ^ ((k&15)<<4) ^ ((k&1)<<8))
__global__ void prep_kernel(const float* __restrict__ cb, float* __restrict__ enorm,
                            char* __restrict__ cb16) {
    int k = blockIdx.x * 4 + (threadIdx.x >> 6);
    int lane = threadIdx.x & 63;
    float4 v = *(const float4*)(cb + k * C_DIM + lane * 4);
    double s = (double)v.x * v.x + (double)v.y * v.y + (double)v.z * v.z + (double)v.w * v.w;
    #pragma unroll
    for (int m = 1; m < 64; m <<= 1) s += __shfl_xor(s, m, 64);
    if (lane == 0) enorm[k] = (float)s;
    f16x4 h;
    h[0] = (_Float16)v.x; h[1] = (_Float16)v.y; h[2] = (_Float16)v.z; h[3] = (_Float16)v.w;
    int dst = ((k >> 4) << 13) + ((k & 15) << 9)
            + ((lane * 8) ^ ((k & 15) << 4) ^ ((k & 1) << 8));
    *(f16x4*)(cb16 + dst) = h;
}

// Kernel 2: single-sweep fp16-MFMA prune; 16-row x 512-code waves; wave-private
// single-LDS-buffer staging (1-ahead prefetch, proven R10/R11 sync); in-register
// top-2 per lane-slot; exact fp64+fp32-sim rescore.
__global__ __launch_bounds__(256, 2) void vq_main(
    const float* __restrict__ x, const float* __restrict__ cb,
    const float* __restrict__ enorm_g, const char* __restrict__ cb16,
    float* __restrict__ out, float* __restrict__ idx_out, float* __restrict__ t2_out)
{
    extern __shared__ char smem[];
    float* qt      = (float*)(smem + OFF_EBUF);   // tail-phase alias (ebuf+en dead)
    float* en_lds  = (float*)(smem + OFF_EN);
    float* S32     = (float*)(smem + OFF_S32);
    float* m1w     = (float*)(smem + OFF_M1W);    // [wave][16]
    float* thr     = (float*)(smem + OFF_THR);
    unsigned long long* res = (unsigned long long*)(smem + OFF_RES);
    int*   fidx    = (int*)(smem + OFF_FIDX);
    int*   lcnt    = (int*)(smem + OFF_LCNT);
    unsigned int* lmeta = (unsigned int*)(smem + OFF_LMETA);

    const int t     = threadIdx.x;
    const int lane  = t & 63;
    const int wv    = t >> 6;
    const int rg    = wv >> 1;         // row group: rows rg*16 .. rg*16+15
    const int chalf = wv & 1;          // code half: codes chalf*512 .. +512
    const int l15   = lane & 15;
    const int l4    = lane >> 4;
    const int row0  = blockIdx.x * ROWS;
    const int b     = row0 >> 10;
    const int hw0   = row0 & 1023;
    const float* xb = x + b * (C_DIM * HW) + hw0;

    char* ebw = smem + OFF_EBUF + wv * WCHUNK_BYTES;     // wave-private 8KB buffer
    const char* cbw = cb16 + (chalf << 9) * 512;         // this wave's 512-code half

    // ---- issue wave-private staging for chunk 0 (lands under the A-build) ----
    {
        const char* src = cbw;                           // ch=0 slice
        #pragma unroll
        for (int i = 0; i < 8; i++) {
            __builtin_amdgcn_global_load_lds((const AS1 unsigned int*)(src + i * 1024 + lane * 16),
                                             (AS3 unsigned int*)(ebw + i * 1024), 16, 0, 0);
        }
    }

    // ---- stage enorm + reset counters ----
    *(float4*)&en_lds[t * 4] = *(const float4*)(enorm_g + t * 4);
    if (t < 4) lcnt[t] = 0;

    // ---- A fragments (16 rows) direct from global x (fp16, scaled by -2) + fp64 S32 ----
    half8 af[8];
    double s64 = 0.0;
    {
        const float* xr = xb + rg * 16 + l15;
        #pragma unroll
        for (int kk = 0; kk < 8; kk++) {
            float v[8];
            #pragma unroll
            for (int j = 0; j < 8; j++) v[j] = xr[(kk * 32 + l4 * 8 + j) * HW];
            #pragma unroll
            for (int j = 0; j < 8; j++) s64 = fma((double)v[j], (double)v[j], s64);
            half8 h;
            #pragma unroll
            for (int j = 0; j < 8; j++) h[j] = (_Float16)(-2.0f * v[j]);
            af[kk] = h;
        }
    }
    s64 += __shfl_xor(s64, 16, 64);
    s64 += __shfl_xor(s64, 32, 64);
    if (chalf == 0 && l4 == 0) S32[rg * 16 + l15] = (float)s64;
    __syncthreads();   // S32/en visible; chunk 0 landed (full drain, once)

    const int swzB = (l15 << 4) ^ ((l15 & 1) << 8);
    const int bofs = (l15 << 9);
    const int enbase = (chalf << 9) + l15;

    // ====== SINGLE SWEEP: 32 chunks of 16 codes; wait -> read -> refill -> MFMA ======
    float s1v[4], s2v[4];
    int   c1v[4], c2v[4];
    #pragma unroll
    for (int r2 = 0; r2 < 4; r2++) {
        s1v[r2] = FLT_MAX; s2v[r2] = FLT_MAX; c1v[r2] = 0; c2v[r2] = 0;
    }

    for (int ch = 0; ch < NCHUNK; ch++) {
        if (ch) { asm volatile("s_waitcnt vmcnt(0)" ::: "memory"); }   // chunk ch landed
        __builtin_amdgcn_sched_barrier(0);

        half8 bf[8];
        #pragma unroll
        for (int kk = 0; kk < 8; kk++)
            bf[kk] = *(const half8*)(ebw + bofs + (((kk << 6) | (l4 << 4)) ^ swzB));
        asm volatile("s_waitcnt lgkmcnt(0)" ::: "memory");   // bf in regs; buffer dead
        __builtin_amdgcn_sched_barrier(0);

        if (ch + 1 < NCHUNK) {       // refill same buffer for ch+1
            const char* src = cbw + (ch + 1) * WCHUNK_BYTES;
            #pragma unroll
            for (int i = 0; i < 8; i++) {
                __builtin_amdgcn_global_load_lds((const AS1 unsigned int*)(src + i * 1024 + lane * 16),
                                                 (AS3 unsigned int*)(ebw + i * 1024), 16, 0, 0);
            }
        }

        const float en = en_lds[enbase + ch * 16];
        f32x4 acc = {en, en, en, en};      // ||e||^2 folded into C-in
        #pragma unroll
        for (int kk = 0; kk < 8; kk++)
            acc = __builtin_amdgcn_mfma_f32_16x16x32_f16(af[kk], bf[kk], acc, 0, 0, 0);

        // lane-local top-2 update per slot (no cross-lane ops)
        #pragma unroll
        for (int r2 = 0; r2 < 4; r2++) {
            float s = acc[r2];
            if (s < s1v[r2]) {
                s2v[r2] = s1v[r2]; c2v[r2] = c1v[r2];
                s1v[r2] = s;       c1v[r2] = ch;
            } else if (s < s2v[r2]) {
                s2v[r2] = s; c2v[r2] = ch;
            }
        }
    }

    // ---- one-time reduce: DPP over 16 lanes -> per-row wave min; cross-wave merge ----
    #pragma unroll
    for (int r2 = 0; r2 < 4; r2++) {
        float m = s1v[r2];
        m = DPP_MIN(m, 0xB1);
        m = DPP_MIN(m, 0x4E);
        m = DPP_MIN(m, 0x141);
        m = DPP_MIN(m, 0x140);   // min over this wave's 16 code-columns
        if (l15 == 0) m1w[wv * 16 + l4 * 4 + r2] = m;
    }
    __syncthreads();
    if (t < 32) {
        int g = t >> 4;          // row group of row t
        thr[t] = fminf(m1w[(g * 2 + 0) * 16 + (t & 15)],
                       m1w[(g * 2 + 1) * 16 + (t & 15)]) + DELTA;
        res[t] = ~0ull;
    }
    __syncthreads();

    // ---- push candidates from register top-2 (once, tiny) ----
    #pragma unroll
    for (int r2 = 0; r2 < 4; r2++) {
        int row_l = rg * 16 + l4 * 4 + r2;
        float tr = thr[row_l];
        if (s1v[r2] < tr) {
            int code = (chalf << 9) + c1v[r2] * 16 + l15;
            int slot = atomicAdd(&lcnt[wv], 1);
            if (slot < LISTCAP)
                lmeta[wv * LISTCAP + slot] = ((unsigned)row_l << 16) | (unsigned)code;
        }
        if (s2v[r2] < tr) {
            int code = (chalf << 9) + c2v[r2] * 16 + l15;
            int slot = atomicAdd(&lcnt[wv], 1);
            if (slot < LISTCAP)
                lmeta[wv * LISTCAP + slot] = ((unsigned)row_l << 16) | (unsigned)code;
        }
    }
    __syncthreads();

    // ---- rescore survivors: fp64 dot (z re-read from global) -> fp32 ref sim ----
    {
        int n = lcnt[wv]; if (n > LISTCAP) n = LISTCAP;
        for (int base = 0; base < n; base += 4) {
            int it = base + l4;
            if (it < n) {
                unsigned meta = lmeta[wv * LISTCAP + it];
                int row  = (int)(meta >> 16);
                int code = (int)(meta & 1023u);
                const float* xr = xb + row;            // element c at xr[c*HW]
                const float* er = cb + code * C_DIM;
                double acc = 0.0;
                #pragma unroll
                for (int s2 = 0; s2 < 16; s2++) {
                    int c = l15 + 16 * s2;
                    acc = fma((double)xr[(size_t)c * HW], (double)er[c], acc);
                }
                acc += __shfl_xor(acc, 1, 64);
                acc += __shfl_xor(acc, 2, 64);
                acc += __shfl_xor(acc, 4, 64);
                acc += __shfl_xor(acc, 8, 64);
                if (l15 == 0) {
                    float Mf = (float)acc;
                    float t2 = __fadd_rn(__fsub_rn(S32[row], __fmul_rn(2.0f, Mf)), en_lds[code]);
                    unsigned long long pk =
                        ((unsigned long long)__float_as_uint(t2) << 32) | (unsigned long long)(unsigned)code;
                    atomicMin(&res[row], pk);
                }
            }
        }
    }
    __syncthreads();

    if (t < 32) {
        unsigned long long v = res[t];
        int code = (int)(v & 1023u);
        fidx[t] = code;
        idx_out[row0 + t] = (float)code;
        t2_out[row0 + t] = __uint_as_float((unsigned)(v >> 32));
    }
    __syncthreads();

    // ---- quantized output (NCHW) via LDS bounce: coalesced reads AND stores ----
    {
        for (int idx = t; idx < 32 * 64; idx += 256) {
            int r  = idx >> 6;         // 0..31
            int c4 = idx & 63;
            const float* er = cb + fidx[r] * C_DIM;
            *(float4*)&qt[r * QT_STRIDE + c4 * 4] = *(const float4*)(er + c4 * 4);
        }
        __syncthreads();
        float* ob = out + b * (C_DIM * HW) + hw0;
        int rr = t & 31;
        int cg = t >> 5;               // 0..7
        for (int cc = cg; cc < C_DIM; cc += 8) {
            ob[cc * HW + rr] = qt[rr * QT_STRIDE + cc];
        }
    }
}

// Kernel 3: deterministic loss reduction over per-row t2
__global__ void loss_kernel(const float* __restrict__ t2min, float* __restrict__ losses) {
    __shared__ double sh[256];
    int t = threadIdx.x;
    double a = 0.0;
    const int per = N_ROWS / 256;
    for (int i = t * per; i < t * per + per; i++) a += (double)t2min[i];
    sh[t] = a;
    __syncthreads();
    for (int s = 128; s > 0; s >>= 1) {
        if (t < s) sh[t] += sh[t + s];
        __syncthreads();
    }
    if (t == 0) {
        double M = sh[0] / (double)OUT_ELEMS;
        losses[0] = (float)(1.25 * M);   // quantizer_loss
        losses[1] = (float)(0.25 * M);   // e_latent_loss
        losses[2] = (float)(M);          // q_latent_loss
    }
}

extern "C" void kernel_launch(void* const* d_in, const int* in_sizes, int n_in,
                              void* d_out, int out_size, void* d_ws, size_t ws_size,
                              hipStream_t stream) {
    const float* x  = (const float*)d_in[0];
    const float* cb = (const float*)d_in[1];
    float* out     = (float*)d_out;
    float* losses  = out + LOSS_OFF;
    float* idx_out = out + IDX_OFF;

    char*  cb16     = (char*)d_ws;                               // 524288 B
    float* t2ws     = (float*)((char*)d_ws + 524288);            // 131072 B
    float* enorm_ws = (float*)((char*)d_ws + 524288 + 131072);   // 4096 B

    hipFuncSetAttribute(reinterpret_cast<const void*>(vq_main),
                        hipFuncAttributeMaxDynamicSharedMemorySize, SMEM_BYTES);

    prep_kernel<<<K_CODES / 4, 256, 0, stream>>>(cb, enorm_ws, cb16);
    vq_main<<<N_ROWS / ROWS, 256, SMEM_BYTES, stream>>>(x, cb, enorm_ws, cb16, out, idx_out, t2ws);
    loss_kernel<<<1, 256, 0, stream>>>(t2ws, losses);
}

// Round 14
// 77.138 us; speedup vs baseline: 2.0398x; 1.1178x over previous
//
#include <hip/hip_runtime.h>
#include <cfloat>

// Problem constants (fixed by setup_inputs)
#define C_DIM   256
#define HW      1024
#define N_ROWS  32768
#define K_CODES 1024
#define ROWS    32            // rows per workgroup; every wave covers all 32 rows
#define NCHUNK  16            // per-wave: 16 chunks x 16 codes = 256 codes (quarter)
#define WCHUNK_BYTES 8192     // 16 codes * 256 * 2B fp16
#define LISTCAP 128           // per-wave candidate list
#define DELTA   0.008f
#define CMASK   0xFFFFFFF0u   // clear low 4 mantissa bits for chunk-id packing

#define OUT_ELEMS 8388608
#define LOSS_OFF  8388608
#define IDX_OFF   8388611

typedef _Float16 half8 __attribute__((ext_vector_type(8)));
typedef _Float16 f16x4 __attribute__((ext_vector_type(4)));
typedef float    f32x4 __attribute__((ext_vector_type(4)));

#define AS1 __attribute__((address_space(1)))
#define AS3 __attribute__((address_space(3)))

// dynamic LDS layout (bytes); qt[32][258] f32 (33024B) tail-aliases ebuf+en (dead then)
#define OFF_EBUF  0                    // 4 waves * 8192 = 32768
#define OFF_EN    32768                // 1024*4 -> 36864
#define OFF_S32   36864                // 32*4 -> 36992
#define OFF_M1W   36992                // 4*32*4 -> 37504
#define OFF_THR   37504                // 32*4 -> 37632
#define OFF_RES   37632                // 32*8 -> 37888
#define OFF_FIDX  37888                // 32*4 -> 38016
#define OFF_LCNT  38016                // pad -> 38144
#define OFF_LMETA 38144                // 4*128*4 -> 40192
#define SMEM_BYTES 40192               // LDS allows 4 blocks/CU; VGPR binds ~3 waves/SIMD

#define QT_STRIDE 258

// min across the 16-lane row group (lanes sharing lane>>4)
#define DPP_MIN(x, ctrl) fminf((x), __int_as_float(__builtin_amdgcn_update_dpp(0, __float_as_int(x), (ctrl), 0xf, 0xf, true)))

// Kernel 1: codebook prep — fp32 norms (fp64-accurate) + fp16 copy, kk-major layout.
// chunk g = k/16 (8192 B each); within chunk:
//   byte = (c/32)*1024 + ((c/8)%4)*256 + (k%16)*16 + (c%8)*2
// => staging instr i covers LDS [i*1024, i*1024+1024) linearly in lane;
//    MFMA B-read for lane: base (l4*256 + l15*16) + imm kk*1024, conflict-free.
__global__ void prep_kernel(const float* __restrict__ cb, float* __restrict__ enorm,
                            char* __restrict__ cb16) {
    int k = blockIdx.x * 4 + (threadIdx.x >> 6);
    int lane = threadIdx.x & 63;
    int c0 = lane * 4;
    float4 v = *(const float4*)(cb + k * C_DIM + c0);
    double s = (double)v.x * v.x + (double)v.y * v.y + (double)v.z * v.z + (double)v.w * v.w;
    #pragma unroll
    for (int m = 1; m < 64; m <<= 1) s += __shfl_xor(s, m, 64);
    if (lane == 0) enorm[k] = (float)s;
    f16x4 h;
    h[0] = (_Float16)v.x; h[1] = (_Float16)v.y; h[2] = (_Float16)v.z; h[3] = (_Float16)v.w;
    int dst = ((k >> 4) << 13) + ((c0 >> 5) << 10) + (((c0 >> 3) & 3) << 8)
            + ((k & 15) << 4) + ((c0 & 7) << 1);
    *(f16x4*)(cb16 + dst) = h;
}

// Kernel 2: single-sweep fp16-MFMA prune; wave = 32 rows x 256 codes (disjoint code
// quarters -> no duplicate staging); kk-major LDS (imm-offset ds_reads); packed
// in-register top-2 (med3/min); exact fp64+fp32-sim rescore.
__global__ __launch_bounds__(256, 2) void vq_main(
    const float* __restrict__ x, const float* __restrict__ cb,
    const float* __restrict__ enorm_g, const char* __restrict__ cb16,
    float* __restrict__ out, float* __restrict__ idx_out, float* __restrict__ t2_out)
{
    extern __shared__ char smem[];
    float* qt      = (float*)(smem + OFF_EBUF);   // tail-phase alias (ebuf+en dead)
    float* en_lds  = (float*)(smem + OFF_EN);
    float* S32     = (float*)(smem + OFF_S32);
    float* m1w     = (float*)(smem + OFF_M1W);    // [wave][32]
    float* thr     = (float*)(smem + OFF_THR);
    unsigned long long* res = (unsigned long long*)(smem + OFF_RES);
    int*   fidx    = (int*)(smem + OFF_FIDX);
    int*   lcnt    = (int*)(smem + OFF_LCNT);
    unsigned int* lmeta = (unsigned int*)(smem + OFF_LMETA);

    const int t    = threadIdx.x;
    const int lane = t & 63;
    const int wq   = t >> 6;           // wave's code quarter: codes wq*256 .. +256
    const int l15  = lane & 15;
    const int l4   = lane >> 4;
    const int row0 = blockIdx.x * ROWS;
    const int b    = row0 >> 10;
    const int hw0  = row0 & 1023;
    const float* xb = x + b * (C_DIM * HW) + hw0;

    char* ebw = smem + OFF_EBUF + wq * WCHUNK_BYTES;     // wave-private 8KB buffer
    const char* cbw = cb16 + wq * (NCHUNK * WCHUNK_BYTES);  // this wave's 256 codes

    // ---- issue wave-private staging for chunk 0 (lands under the A-build) ----
    #pragma unroll
    for (int i = 0; i < 8; i++) {
        __builtin_amdgcn_global_load_lds((const AS1 unsigned int*)(cbw + i * 1024 + lane * 16),
                                         (AS3 unsigned int*)(ebw + i * 1024), 16, 0, 0);
    }

    // ---- stage enorm + reset counters ----
    *(float4*)&en_lds[t * 4] = *(const float4*)(enorm_g + t * 4);
    if (t < 4) lcnt[t] = 0;

    // ---- A fragments (32 rows) direct from global x (fp16, scaled by -2) + fp64 S32 ----
    half8 af[2][8];
    double s64[2] = {0.0, 0.0};
    #pragma unroll
    for (int rt = 0; rt < 2; rt++) {
        const float* xr = xb + rt * 16 + l15;
        #pragma unroll
        for (int kk = 0; kk < 8; kk++) {
            float v[8];
            #pragma unroll
            for (int j = 0; j < 8; j++) v[j] = xr[(kk * 32 + l4 * 8 + j) * HW];
            #pragma unroll
            for (int j = 0; j < 8; j++) s64[rt] = fma((double)v[j], (double)v[j], s64[rt]);
            half8 h;
            #pragma unroll
            for (int j = 0; j < 8; j++) h[j] = (_Float16)(-2.0f * v[j]);
            af[rt][kk] = h;
        }
    }
    #pragma unroll
    for (int rt = 0; rt < 2; rt++) {
        s64[rt] += __shfl_xor(s64[rt], 16, 64);
        s64[rt] += __shfl_xor(s64[rt], 32, 64);
    }
    if (wq == 0 && l4 == 0) {
        S32[l15]      = (float)s64[0];
        S32[16 + l15] = (float)s64[1];
    }
    __syncthreads();   // S32/en visible; chunk 0 landed (full drain, once)

    const int bbase  = (l4 << 8) + (l15 << 4);   // ds base; kk adds imm kk*1024
    const int enbase = wq * 256 + l15;

    // ====== SINGLE SWEEP: 16 chunks of 16 codes; packed top-2 per lane-slot ======
    float u1[2][4], u2[2][4];
    #pragma unroll
    for (int rt = 0; rt < 2; rt++)
        #pragma unroll
        for (int r2 = 0; r2 < 4; r2++) { u1[rt][r2] = FLT_MAX; u2[rt][r2] = FLT_MAX; }

    for (int ch = 0; ch < NCHUNK; ch++) {
        if (ch) { asm volatile("s_waitcnt vmcnt(0)" ::: "memory"); }   // chunk ch landed
        __builtin_amdgcn_sched_barrier(0);

        half8 bf[8];
        #pragma unroll
        for (int kk = 0; kk < 8; kk++)
            bf[kk] = *(const half8*)(ebw + bbase + (kk << 10));
        asm volatile("s_waitcnt lgkmcnt(0)" ::: "memory");   // bf in regs; buffer dead
        __builtin_amdgcn_sched_barrier(0);

        if (ch + 1 < NCHUNK) {       // refill same buffer for ch+1
            const char* src = cbw + (ch + 1) * WCHUNK_BYTES;
            #pragma unroll
            for (int i = 0; i < 8; i++) {
                __builtin_amdgcn_global_load_lds((const AS1 unsigned int*)(src + i * 1024 + lane * 16),
                                                 (AS3 unsigned int*)(ebw + i * 1024), 16, 0, 0);
            }
        }

        const float en = en_lds[enbase + ch * 16];
        f32x4 acc0 = {en, en, en, en};      // ||e||^2 folded into C-in
        f32x4 acc1 = {en, en, en, en};
        #pragma unroll
        for (int kk = 0; kk < 8; kk++) {
            acc0 = __builtin_amdgcn_mfma_f32_16x16x32_f16(af[0][kk], bf[kk], acc0, 0, 0, 0);
            acc1 = __builtin_amdgcn_mfma_f32_16x16x32_f16(af[1][kk], bf[kk], acc1, 0, 0, 0);
        }
        // packed top-2: chunk id in low 4 mantissa bits (<=2e-5 perturbation << DELTA)
        #pragma unroll
        for (int r2 = 0; r2 < 4; r2++) {
            float ua = __uint_as_float((__float_as_uint(acc0[r2]) & CMASK) | (unsigned)ch);
            u2[0][r2] = __builtin_amdgcn_fmed3f(ua, u1[0][r2], u2[0][r2]);
            u1[0][r2] = fminf(u1[0][r2], ua);
            float ub = __uint_as_float((__float_as_uint(acc1[r2]) & CMASK) | (unsigned)ch);
            u2[1][r2] = __builtin_amdgcn_fmed3f(ub, u1[1][r2], u2[1][r2]);
            u1[1][r2] = fminf(u1[1][r2], ub);
        }
    }

    // ---- one-time reduce: DPP over 16 lanes -> per-row wave min; cross-wave merge ----
    #pragma unroll
    for (int rt = 0; rt < 2; rt++) {
        #pragma unroll
        for (int r2 = 0; r2 < 4; r2++) {
            float m = u1[rt][r2];
            m = DPP_MIN(m, 0xB1);
            m = DPP_MIN(m, 0x4E);
            m = DPP_MIN(m, 0x141);
            m = DPP_MIN(m, 0x140);   // min over this wave's 16 code-columns
            if (l15 == 0) m1w[wq * 32 + rt * 16 + l4 * 4 + r2] = m;
        }
    }
    __syncthreads();
    if (t < 32) {
        thr[t] = fminf(fminf(m1w[t], m1w[32 + t]), fminf(m1w[64 + t], m1w[96 + t])) + DELTA;
        res[t] = ~0ull;
    }
    __syncthreads();

    // ---- push candidates from register top-2 (once, tiny) ----
    #pragma unroll
    for (int rt = 0; rt < 2; rt++) {
        #pragma unroll
        for (int r2 = 0; r2 < 4; r2++) {
            int row_l = rt * 16 + l4 * 4 + r2;
            float tr = thr[row_l];
            if (u1[rt][r2] < tr) {
                int ch1 = (int)(__float_as_uint(u1[rt][r2]) & 15u);
                int code = wq * 256 + ch1 * 16 + l15;
                int slot = atomicAdd(&lcnt[wq], 1);
                if (slot < LISTCAP)
                    lmeta[wq * LISTCAP + slot] = ((unsigned)row_l << 16) | (unsigned)code;
            }
            if (u2[rt][r2] < tr) {
                int ch2 = (int)(__float_as_uint(u2[rt][r2]) & 15u);
                int code = wq * 256 + ch2 * 16 + l15;
                int slot = atomicAdd(&lcnt[wq], 1);
                if (slot < LISTCAP)
                    lmeta[wq * LISTCAP + slot] = ((unsigned)row_l << 16) | (unsigned)code;
            }
        }
    }
    __syncthreads();

    // ---- rescore survivors: fp64 dot (z re-read from global) -> fp32 ref sim ----
    {
        int n = lcnt[wq]; if (n > LISTCAP) n = LISTCAP;
        for (int base = 0; base < n; base += 4) {
            int it = base + l4;
            if (it < n) {
                unsigned meta = lmeta[wq * LISTCAP + it];
                int row  = (int)(meta >> 16);
                int code = (int)(meta & 1023u);
                const float* xr = xb + row;            // element c at xr[c*HW]
                const float* er = cb + code * C_DIM;
                double acc = 0.0;
                #pragma unroll
                for (int s2 = 0; s2 < 16; s2++) {
                    int c = l15 + 16 * s2;
                    acc = fma((double)xr[(size_t)c * HW], (double)er[c], acc);
                }
                acc += __shfl_xor(acc, 1, 64);
                acc += __shfl_xor(acc, 2, 64);
                acc += __shfl_xor(acc, 4, 64);
                acc += __shfl_xor(acc, 8, 64);
                if (l15 == 0) {
                    float Mf = (float)acc;
                    float t2 = __fadd_rn(__fsub_rn(S32[row], __fmul_rn(2.0f, Mf)), en_lds[code]);
                    unsigned long long pk =
                        ((unsigned long long)__float_as_uint(t2) << 32) | (unsigned long long)(unsigned)code;
                    atomicMin(&res[row], pk);
                }
            }
        }
    }
    __syncthreads();

    if (t < 32) {
        unsigned long long v = res[t];
        int code = (int)(v & 1023u);
        fidx[t] = code;
        idx_out[row0 + t] = (float)code;
        t2_out[row0 + t] = __uint_as_float((unsigned)(v >> 32));
    }
    __syncthreads();

    // ---- quantized output (NCHW) via LDS bounce: coalesced reads AND stores ----
    {
        for (int idx = t; idx < 32 * 64; idx += 256) {
            int r  = idx >> 6;         // 0..31
            int c4 = idx & 63;
            const float* er = cb + fidx[r] * C_DIM;
            *(float4*)&qt[r * QT_STRIDE + c4 * 4] = *(const float4*)(er + c4 * 4);
        }
        __syncthreads();
        float* ob = out + b * (C_DIM * HW) + hw0;
        int rr = t & 31;
        int cg = t >> 5;               // 0..7
        for (int cc = cg; cc < C_DIM; cc += 8) {
            ob[cc * HW + rr] = qt[rr * QT_STRIDE + cc];
        }
    }
}

// Kernel 3: deterministic loss reduction over per-row t2
__global__ void loss_kernel(const float* __restrict__ t2min, float* __restrict__ losses) {
    __shared__ double sh[256];
    int t = threadIdx.x;
    double a = 0.0;
    const int per = N_ROWS / 256;
    for (int i = t * per; i < t * per + per; i++) a += (double)t2min[i];
    sh[t] = a;
    __syncthreads();
    for (int s = 128; s > 0; s >>= 1) {
        if (t < s) sh[t] += sh[t + s];
        __syncthreads();
    }
    if (t == 0) {
        double M = sh[0] / (double)OUT_ELEMS;
        losses[0] = (float)(1.25 * M);   // quantizer_loss
        losses[1] = (float)(0.25 * M);   // e_latent_loss
        losses[2] = (float)(M);          // q_latent_loss
    }
}

extern "C" void kernel_launch(void* const* d_in, const int* in_sizes, int n_in,
                              void* d_out, int out_size, void* d_ws, size_t ws_size,
                              hipStream_t stream) {
    const float* x  = (const float*)d_in[0];
    const float* cb = (const float*)d_in[1];
    float* out     = (float*)d_out;
    float* losses  = out + LOSS_OFF;
    float* idx_out = out + IDX_OFF;

    char*  cb16     = (char*)d_ws;                               // 524288 B
    float* t2ws     = (float*)((char*)d_ws + 524288);            // 131072 B
    float* enorm_ws = (float*)((char*)d_ws + 524288 + 131072);   // 4096 B

    hipFuncSetAttribute(reinterpret_cast<const void*>(vq_main),
                        hipFuncAttributeMaxDynamicSharedMemorySize, SMEM_BYTES);

    prep_kernel<<<K_CODES / 4, 256, 0, stream>>>(cb, enorm_ws, cb16);
    vq_main<<<N_ROWS / ROWS, 256, SMEM_BYTES, stream>>>(x, cb, enorm_ws, cb16, out, idx_out, t2ws);
    loss_kernel<<<1, 256, 0, stream>>>(t2ws, losses);
}